// Round 10
// baseline (1304.743 us; speedup 1.0000x reference)
//
#include <hip/hip_runtime.h>
#include <math.h>

#define BATCH 4
#define NPTS 1024
#define KNN 20
#define EPS 1e-5f
#define FEATC 2048
#define KC 16

// Workspace budget note (R4 post-mortem): total footprint kept under 67 MB.
// R8: xx == diag(G) bitwise; R9: diag folded into gram epilogue directly.
// R9: split-lane 128x128 tiles (8x8/thread) for gram(L5/L6) and pq(L6):
// every LDS read is a stride-4 float4 (2-way = free), 0.75 B/FMA vs 1.5.

// ---------------- Gram 64(n) x 128(m), 4x8/thread (L1-L4) ----------------
__global__ __launch_bounds__(256, 2)
void gram_kernel(const float* __restrict__ x, int Cin, size_t bstride,
                 float* __restrict__ G, float* __restrict__ xx) {
    // grid: (NPTS/128, NPTS/64, BATCH); block 256 = 16(tn) x 16(tm)
    int b = blockIdx.z;
    int n0 = blockIdx.y * 64;
    int m0 = blockIdx.x * 128;
    const float* xb = x + (size_t)b * bstride;
    __shared__ float As[KC][64];
    __shared__ float Bs[KC][128];
    int tid = threadIdx.x;
    int tn = tid % 16, tm = tid / 16;
    float acc[4][8] = {};

    const int ia = tid * 4, cca = ia >> 6, nna = ia & 63;
    const int ib = tid * 8, ccb = ib >> 7, mmb = ib & 127;
    float4 pa, pb0, pb1;
    auto prefetch = [&](int c0) {
        pa = make_float4(0.f, 0.f, 0.f, 0.f);
        pb0 = make_float4(0.f, 0.f, 0.f, 0.f);
        pb1 = make_float4(0.f, 0.f, 0.f, 0.f);
        if (c0 + cca < Cin) pa = *(const float4*)(xb + (size_t)(c0 + cca) * NPTS + n0 + nna);
        if (c0 + ccb < Cin) {
            const float* r = xb + (size_t)(c0 + ccb) * NPTS + m0 + mmb;
            pb0 = *(const float4*)(r);
            pb1 = *(const float4*)(r + 4);
        }
    };
    prefetch(0);
    for (int c0 = 0; c0 < Cin; c0 += KC) {
        *(float4*)(&As[cca][nna]) = pa;
        *(float4*)(&Bs[ccb][mmb]) = pb0;
        *(float4*)(&Bs[ccb][mmb + 4]) = pb1;
        __syncthreads();
        if (c0 + KC < Cin) prefetch(c0 + KC);
#pragma unroll
        for (int cc = 0; cc < KC; ++cc) {
            float4 a4 = *(const float4*)(&As[cc][tn * 4]);
            float4 b0 = *(const float4*)(&Bs[cc][tm * 8]);
            float4 b1 = *(const float4*)(&Bs[cc][tm * 8 + 4]);
            float a[4] = {a4.x, a4.y, a4.z, a4.w};
            float bb[8] = {b0.x, b0.y, b0.z, b0.w, b1.x, b1.y, b1.z, b1.w};
#pragma unroll
            for (int i = 0; i < 4; i++)
#pragma unroll
                for (int j = 0; j < 8; j++) acc[i][j] += a[i] * bb[j];
        }
        __syncthreads();
    }
    float* Gb = G + (size_t)b * NPTS * NPTS;
#pragma unroll
    for (int i = 0; i < 4; i++) {
        int n = n0 + tn * 4 + i;
        size_t row = (size_t)n * NPTS + m0 + tm * 8;
        *(float4*)(Gb + row)     = make_float4(acc[i][0], acc[i][1], acc[i][2], acc[i][3]);
        *(float4*)(Gb + row + 4) = make_float4(acc[i][4], acc[i][5], acc[i][6], acc[i][7]);
        // diag fold (R8/R9): xx[b][n] = G[b][n][n]
#pragma unroll
        for (int j = 0; j < 8; j++)
            if (n == m0 + tm * 8 + j) xx[b * NPTS + n] = acc[i][j];
    }
}

// ---------------- Gram 128x128, 8x8/thread, split lanes (L5/L6) ----------------
__global__ __launch_bounds__(256, 2)
void gram128_kernel(const float* __restrict__ x, int Cin, size_t bstride,
                    float* __restrict__ G, float* __restrict__ xx) {
    // grid: (NPTS/128, NPTS/128, BATCH); block 256 = 16(tn:n) x 16(tm:m)
    int b = blockIdx.z;
    int n0 = blockIdx.y * 128;
    int m0 = blockIdx.x * 128;
    const float* xb = x + (size_t)b * bstride;
    __shared__ float As[KC][128];
    __shared__ float Bs[KC][128];
    int tid = threadIdx.x;
    int tn = tid % 16, tm = tid / 16;
    float acc[8][8] = {};

    const int cca = tid / 16, nna = (tid * 8) & 127;  // tid*8: cc=tid/16
    float4 pa0, pa1, pb0, pb1;
    auto prefetch = [&](int c0) {
        const float* ra = xb + (size_t)(c0 + cca) * NPTS + n0 + nna;
        const float* rb = xb + (size_t)(c0 + cca) * NPTS + m0 + nna;
        pa0 = *(const float4*)(ra);
        pa1 = *(const float4*)(ra + 4);
        pb0 = *(const float4*)(rb);
        pb1 = *(const float4*)(rb + 4);
    };
    prefetch(0);
    for (int c0 = 0; c0 < Cin; c0 += KC) {
        *(float4*)(&As[cca][nna]) = pa0;
        *(float4*)(&As[cca][nna + 4]) = pa1;
        *(float4*)(&Bs[cca][nna]) = pb0;
        *(float4*)(&Bs[cca][nna + 4]) = pb1;
        __syncthreads();
        if (c0 + KC < Cin) prefetch(c0 + KC);
#pragma unroll
        for (int cc = 0; cc < KC; ++cc) {
            float4 a0 = *(const float4*)(&As[cc][tn * 4]);
            float4 a1 = *(const float4*)(&As[cc][64 + tn * 4]);
            float4 b0 = *(const float4*)(&Bs[cc][tm * 4]);
            float4 b1 = *(const float4*)(&Bs[cc][64 + tm * 4]);
            float a[8] = {a0.x, a0.y, a0.z, a0.w, a1.x, a1.y, a1.z, a1.w};
            float bb[8] = {b0.x, b0.y, b0.z, b0.w, b1.x, b1.y, b1.z, b1.w};
#pragma unroll
            for (int i = 0; i < 8; i++)
#pragma unroll
                for (int j = 0; j < 8; j++) acc[i][j] += a[i] * bb[j];
        }
        __syncthreads();
    }
    float* Gb = G + (size_t)b * NPTS * NPTS;
#pragma unroll
    for (int i = 0; i < 8; i++) {
        int n = n0 + (i < 4 ? tn * 4 + i : 64 + tn * 4 + (i - 4));
        size_t row = (size_t)n * NPTS;
        *(float4*)(Gb + row + m0 + tm * 4)      = make_float4(acc[i][0], acc[i][1], acc[i][2], acc[i][3]);
        *(float4*)(Gb + row + m0 + 64 + tm * 4) = make_float4(acc[i][4], acc[i][5], acc[i][6], acc[i][7]);
#pragma unroll
        for (int j = 0; j < 8; j++) {
            int m = m0 + (j < 4 ? tm * 4 + j : 64 + tm * 4 + (j - 4));
            if (n == m) xx[b * NPTS + n] = acc[i][j];
        }
    }
}

// ---------------- top-K: one wave per row, barrier-free (R6 rewrite) ----------------
__global__ __launch_bounds__(256)
void topk_kernel(const float* __restrict__ G, const float* __restrict__ xx,
                 int* __restrict__ idx) {
    // grid BATCH*NPTS/4
    int wid = threadIdx.x >> 6, lane = threadIdx.x & 63;
    int t = blockIdx.x * 4 + wid;
    int b = t >> 10, n = t & (NPTS - 1);
    const float* Gr = G + ((size_t)b * NPTS + n) * NPTS;
    const float* xxb = xx + b * NPTS;
    float xxn = xxb[n];
    float d[16];
    int base = lane * 4;
#pragma unroll
    for (int c = 0; c < 4; ++c) {
        float4 gv = *(const float4*)(Gr + c * 256 + base);
        float4 xv = *(const float4*)(xxb + c * 256 + base);
        d[c * 4 + 0] = (2.f * gv.x - xxn) - xv.x;
        d[c * 4 + 1] = (2.f * gv.y - xxn) - xv.y;
        d[c * 4 + 2] = (2.f * gv.z - xxn) - xv.z;
        d[c * 4 + 3] = (2.f * gv.w - xxn) - xv.w;
    }
    int* out = idx + (size_t)t * KNN;
    for (int k = 0; k < KNN; ++k) {
        float bv = d[0]; int bs = 0;
#pragma unroll
        for (int s = 1; s < 16; ++s)
            if (d[s] > bv) { bv = d[s]; bs = s; }
        int bm = ((bs >> 2) << 8) + base + (bs & 3);
#pragma unroll
        for (int off = 32; off >= 1; off >>= 1) {
            float ov = __shfl_xor(bv, off);
            int om = __shfl_xor(bm, off);
            if (ov > bv || (ov == bv && om < bm)) { bv = ov; bm = om; }
        }
        if (lane == 0) out[k] = bm;
        int rel = bm - base;
#pragma unroll
        for (int s = 0; s < 16; ++s)
            if (rel == (((s >> 2) << 8) | (s & 3))) d[s] = -INFINITY;
    }
}

// ---------------- p/q 64x64 tile, 4x4/thread (L1-L5) ----------------
__global__ __launch_bounds__(256, 2)
void pq_gemm_kernel(const float* __restrict__ x, int Cin, size_t bstride,
                    const float* __restrict__ W, int Cout,
                    float* __restrict__ p, float* __restrict__ q) {
    // grid: (Cout/64, NPTS/64, BATCH); block 256 = 16(tn:o) x 16(tm:n)
    int b = blockIdx.z;
    int o0 = blockIdx.x * 64;
    int n0 = blockIdx.y * 64;
    const float* xb = x + (size_t)b * bstride;
    __shared__ float W1s[KC][64];
    __shared__ float WQs[KC][64];
    __shared__ float Xs[KC][64];
    int tid = threadIdx.x;
    int tn = tid % 16;
    int tm = tid / 16;
    float accp[4][4] = {};
    float accq[4][4] = {};

    const int ix = tid * 4, ccx = ix >> 6, nnx = ix & 63;
    const int r = tid % 64, cg = (tid / 64) * 4;
    const float* Wr = W + (size_t)(o0 + r) * 2 * Cin;
    float4 px, pw1, pw2;
    auto prefetch = [&](int c0) {
        px = make_float4(0.f, 0.f, 0.f, 0.f);
        pw1 = make_float4(0.f, 0.f, 0.f, 0.f);
        pw2 = make_float4(0.f, 0.f, 0.f, 0.f);
        if (c0 + ccx < Cin) px = *(const float4*)(xb + (size_t)(c0 + ccx) * NPTS + n0 + nnx);
        if (c0 + cg < Cin) {
            pw1 = *(const float4*)(Wr + c0 + cg);
            pw2 = *(const float4*)(Wr + Cin + c0 + cg);
        }
    };
    prefetch(0);
    for (int c0 = 0; c0 < Cin; c0 += KC) {
        *(float4*)(&Xs[ccx][nnx]) = px;
        W1s[cg + 0][r] = pw1.x; WQs[cg + 0][r] = pw2.x - pw1.x;
        W1s[cg + 1][r] = pw1.y; WQs[cg + 1][r] = pw2.y - pw1.y;
        W1s[cg + 2][r] = pw1.z; WQs[cg + 2][r] = pw2.z - pw1.z;
        W1s[cg + 3][r] = pw1.w; WQs[cg + 3][r] = pw2.w - pw1.w;
        __syncthreads();
        if (c0 + KC < Cin) prefetch(c0 + KC);
#pragma unroll
        for (int cc = 0; cc < KC; ++cc) {
            float4 wv = *(const float4*)(&W1s[cc][tn * 4]);
            float4 qv = *(const float4*)(&WQs[cc][tn * 4]);
            float4 xv = *(const float4*)(&Xs[cc][tm * 4]);
            float w1[4] = {wv.x, wv.y, wv.z, wv.w};
            float wq[4] = {qv.x, qv.y, qv.z, qv.w};
            float xj[4] = {xv.x, xv.y, xv.z, xv.w};
#pragma unroll
            for (int i = 0; i < 4; i++)
#pragma unroll
                for (int j = 0; j < 4; j++) {
                    accp[i][j] += w1[i] * xj[j];
                    accq[i][j] += wq[i] * xj[j];
                }
        }
        __syncthreads();
    }
#pragma unroll
    for (int j = 0; j < 4; j++) {
        int n = n0 + tm * 4 + j;
        size_t base = ((size_t)b * NPTS + n) * Cout + o0 + tn * 4;
        *(float4*)(p + base) = make_float4(accp[0][j], accp[1][j], accp[2][j], accp[3][j]);
        *(float4*)(q + base) = make_float4(accq[0][j], accq[1][j], accq[2][j], accq[3][j]);
    }
}

// ---------------- p/q 128x128 tile, 8x8/thread, split lanes (L6) ----------------
__global__ __launch_bounds__(256, 2)
void pq128_kernel(const float* __restrict__ x, int Cin, size_t bstride,
                  const float* __restrict__ W, int Cout,
                  float* __restrict__ p, float* __restrict__ q) {
    // grid: (Cout/128, NPTS/128, BATCH); block 256 = 16(tn:o) x 16(tm:n)
    int b = blockIdx.z;
    int o0 = blockIdx.x * 128;
    int n0 = blockIdx.y * 128;
    const float* xb = x + (size_t)b * bstride;
    __shared__ float W1s[KC][128];
    __shared__ float WQs[KC][128];
    __shared__ float Xs[KC][128];
    int tid = threadIdx.x;
    int tn = tid % 16;
    int tm = tid / 16;
    float accp[8][8] = {};
    float accq[8][8] = {};

    const int ccx = tid / 16, nnx = (tid * 8) & 127;
    const int r = tid % 128, cg = (tid / 128) * 8;
    const float* Wr = W + (size_t)(o0 + r) * 2 * Cin;
    float4 px0, px1, pw1a, pw1b, pw2a, pw2b;
    auto prefetch = [&](int c0) {
        const float* rx = xb + (size_t)(c0 + ccx) * NPTS + n0 + nnx;
        px0 = *(const float4*)(rx);
        px1 = *(const float4*)(rx + 4);
        pw1a = *(const float4*)(Wr + c0 + cg);
        pw1b = *(const float4*)(Wr + c0 + cg + 4);
        pw2a = *(const float4*)(Wr + Cin + c0 + cg);
        pw2b = *(const float4*)(Wr + Cin + c0 + cg + 4);
    };
    prefetch(0);
    for (int c0 = 0; c0 < Cin; c0 += KC) {
        *(float4*)(&Xs[ccx][nnx]) = px0;
        *(float4*)(&Xs[ccx][nnx + 4]) = px1;
        W1s[cg + 0][r] = pw1a.x; WQs[cg + 0][r] = pw2a.x - pw1a.x;
        W1s[cg + 1][r] = pw1a.y; WQs[cg + 1][r] = pw2a.y - pw1a.y;
        W1s[cg + 2][r] = pw1a.z; WQs[cg + 2][r] = pw2a.z - pw1a.z;
        W1s[cg + 3][r] = pw1a.w; WQs[cg + 3][r] = pw2a.w - pw1a.w;
        W1s[cg + 4][r] = pw1b.x; WQs[cg + 4][r] = pw2b.x - pw1b.x;
        W1s[cg + 5][r] = pw1b.y; WQs[cg + 5][r] = pw2b.y - pw1b.y;
        W1s[cg + 6][r] = pw1b.z; WQs[cg + 6][r] = pw2b.z - pw1b.z;
        W1s[cg + 7][r] = pw1b.w; WQs[cg + 7][r] = pw2b.w - pw1b.w;
        __syncthreads();
        if (c0 + KC < Cin) prefetch(c0 + KC);
#pragma unroll
        for (int cc = 0; cc < KC; ++cc) {
            float4 w0 = *(const float4*)(&W1s[cc][tn * 4]);
            float4 w1v = *(const float4*)(&W1s[cc][64 + tn * 4]);
            float4 q0 = *(const float4*)(&WQs[cc][tn * 4]);
            float4 q1 = *(const float4*)(&WQs[cc][64 + tn * 4]);
            float4 x0 = *(const float4*)(&Xs[cc][tm * 4]);
            float4 x1 = *(const float4*)(&Xs[cc][64 + tm * 4]);
            float w1[8] = {w0.x, w0.y, w0.z, w0.w, w1v.x, w1v.y, w1v.z, w1v.w};
            float wq[8] = {q0.x, q0.y, q0.z, q0.w, q1.x, q1.y, q1.z, q1.w};
            float xj[8] = {x0.x, x0.y, x0.z, x0.w, x1.x, x1.y, x1.z, x1.w};
#pragma unroll
            for (int i = 0; i < 8; i++)
#pragma unroll
                for (int j = 0; j < 8; j++) {
                    accp[i][j] += w1[i] * xj[j];
                    accq[i][j] += wq[i] * xj[j];
                }
        }
        __syncthreads();
    }
#pragma unroll
    for (int j = 0; j < 8; j++) {
        int n = n0 + (j < 4 ? tm * 4 + j : 64 + tm * 4 + (j - 4));
        size_t base = ((size_t)b * NPTS + n) * Cout + o0;
        *(float4*)(p + base + tn * 4)      = make_float4(accp[0][j], accp[1][j], accp[2][j], accp[3][j]);
        *(float4*)(p + base + 64 + tn * 4) = make_float4(accp[4][j], accp[5][j], accp[6][j], accp[7][j]);
        *(float4*)(q + base + tn * 4)      = make_float4(accq[0][j], accq[1][j], accq[2][j], accq[3][j]);
        *(float4*)(q + base + 64 + tn * 4) = make_float4(accq[4][j], accq[5][j], accq[6][j], accq[7][j]);
    }
}

// ---------------- stats pass 1: BN sum/sumsq (deterministic partials) ----------------
template <int COUT>
__global__ void stats_kernel(const float* __restrict__ p, const float* __restrict__ q,
                             const int* __restrict__ idx,
                             float* __restrict__ partials) {
    constexpr int CA = (COUT < 256) ? COUT : 256;
    constexpr int PP = 256 / CA;
    constexpr int NCH = COUT / CA;
    constexpr int NCHUNK = 16;
    int bid = blockIdx.x;
    int b = bid / (NPTS / NCHUNK);
    int n0 = (bid % (NPTS / NCHUNK)) * NCHUNK;
    int cl = threadIdx.x % CA;
    int c = blockIdx.y * CA + cl;
    int sub = threadIdx.x / CA;
    float s = 0.f, ss = 0.f;
    for (int nl = sub; nl < NCHUNK; nl += PP) {
        int n = n0 + nl;
        size_t nb = (size_t)b * NPTS + n;
        const int* ix = idx + nb * KNN;
        float qv = q[nb * COUT + c];
        for (int k = 0; k < KNN; ++k) {
            int m = ix[k];
            float v = p[((size_t)b * NPTS + m) * COUT + c] + qv;
            s += v;
            ss += v * v;
        }
    }
    __shared__ float red[256];
    float* outp = partials + ((size_t)bid * NCH + blockIdx.y) * 2 * CA;
    red[threadIdx.x] = s;
    __syncthreads();
    for (int st = PP / 2; st > 0; st >>= 1) {
        if (sub < st) red[threadIdx.x] += red[threadIdx.x + st * CA];
        __syncthreads();
    }
    if (sub == 0) outp[cl] = red[cl];
    __syncthreads();
    red[threadIdx.x] = ss;
    __syncthreads();
    for (int st = PP / 2; st > 0; st >>= 1) {
        if (sub < st) red[threadIdx.x] += red[threadIdx.x + st * CA];
        __syncthreads();
    }
    if (sub == 0) outp[CA + cl] = red[cl];
}

// ---------------- BN scale/shift from partials (deterministic serial reduce) ----------------
__global__ void scaleshift_kernel(const float* __restrict__ partials, const float* __restrict__ g,
                                  const float* __restrict__ beta, int Cout, int nblk,
                                  int CA, int NCH, float* __restrict__ sc) {
    int c = blockIdx.x * 256 + threadIdx.x;
    if (c >= Cout) return;
    int chunk = c / CA, within = c % CA;
    float s0 = 0.f, s1 = 0.f;
    for (int b = 0; b < nblk; ++b) {
        const float* pp = partials + ((size_t)b * NCH + chunk) * 2 * CA;
        s0 += pp[within];
        s1 += pp[CA + within];
    }
    float cnt = (float)(BATCH * NPTS * KNN);
    float mean = s0 / cnt;
    float var = s1 / cnt - mean * mean;
    float s = g[c] * rsqrtf(var + EPS);
    sc[c] = s;
    sc[Cout + c] = beta[c] - mean * s;
}

// ---------------- pass 2: gather max/min, BN+leaky, transpose to (B, C, N) feat ----------------
__global__ void apply_kernel(const float* __restrict__ p, const float* __restrict__ q,
                             const int* __restrict__ idx, const float* __restrict__ sc,
                             int Cout, int choff, float* __restrict__ feat) {
    // grid: (Cout/32, NPTS/32, BATCH); block 256 = 32 (c) x 8 (n-sub)
    __shared__ float tile[32][33];
    __shared__ int nidx[32][KNN];
    int b = blockIdx.z;
    int c0 = blockIdx.x * 32, n0 = blockIdx.y * 32;
    int tx = threadIdx.x % 32, ty = threadIdx.x / 32;
    for (int i = threadIdx.x; i < 32 * KNN; i += 256) {
        int nn = i / KNN, kk = i % KNN;
        nidx[nn][kk] = idx[((size_t)b * NPTS + n0 + nn) * KNN + kk];
    }
    __syncthreads();
    int c = c0 + tx;
    float s = sc[c], sh = sc[Cout + c];
    for (int i = ty; i < 32; i += 8) {
        int n = n0 + i;
        size_t nb = (size_t)b * NPTS + n;
        float qv = q[nb * Cout + c];
        float mx = -INFINITY, mn = INFINITY;
        for (int k = 0; k < KNN; ++k) {
            int m = nidx[i][k];
            float v = p[((size_t)b * NPTS + m) * Cout + c] + qv;
            mx = fmaxf(mx, v);
            mn = fminf(mn, v);
        }
        float v = (s >= 0.f) ? mx : mn;
        v = s * v + sh;
        tile[i][tx] = (v > 0.f) ? v : 0.2f * v;
    }
    __syncthreads();
    for (int i = ty; i < 32; i += 8) {
        feat[((size_t)b * FEATC + choff + c0 + i) * NPTS + n0 + tx] = tile[tx][i];
    }
}

// ---------------- pooling: max and mean over N ----------------
__global__ void pool_kernel(const float* __restrict__ feat, float* __restrict__ pooled) {
    // grid BATCH*FEATC, block 256
    int t = blockIdx.x;
    int b = t >> 11, c = t & (FEATC - 1);
    const float* row = feat + (size_t)t * NPTS;
    int tid = threadIdx.x;
    float mx = -INFINITY, sm = 0.f;
    for (int n = tid; n < NPTS; n += 256) { float v = row[n]; mx = fmaxf(mx, v); sm += v; }
    __shared__ float smx[256], ssm[256];
    smx[tid] = mx; ssm[tid] = sm;
    __syncthreads();
    for (int s = 128; s > 0; s >>= 1) {
        if (tid < s) { smx[tid] = fmaxf(smx[tid], smx[tid + s]); ssm[tid] += ssm[tid + s]; }
        __syncthreads();
    }
    if (tid == 0) {
        pooled[b * 4096 + c] = smx[0];
        pooled[b * 4096 + 2048 + c] = ssm[0] * (1.f / NPTS);
    }
}

// ---------------- final GEMV + batch-BN + leaky ----------------
__global__ void final_kernel(const float* __restrict__ pooled, const float* __restrict__ Wm,
                             const float* __restrict__ bm, const float* __restrict__ gm,
                             const float* __restrict__ betam, float* __restrict__ out) {
    // grid 512, block 256
    int o = blockIdx.x;
    int tid = threadIdx.x;
    float acc[BATCH] = {};
    for (int t = tid; t < 4096; t += 256) {
        float w = Wm[(size_t)o * 4096 + t];
#pragma unroll
        for (int b = 0; b < BATCH; b++) acc[b] += w * pooled[b * 4096 + t];
    }
    __shared__ float red[256];
    float zb[BATCH];
    for (int b = 0; b < BATCH; b++) {
        red[tid] = acc[b];
        __syncthreads();
        for (int s = 128; s > 0; s >>= 1) {
            if (tid < s) red[tid] += red[tid + s];
            __syncthreads();
        }
        zb[b] = red[0];
        __syncthreads();
    }
    if (tid == 0) {
        float z[BATCH];
        float mean = 0.f;
        for (int b = 0; b < BATCH; b++) { z[b] = zb[b] + bm[o]; mean += z[b]; }
        mean *= (1.f / BATCH);
        float var = 0.f;
        for (int b = 0; b < BATCH; b++) { float d = z[b] - mean; var += d * d; }
        var *= (1.f / BATCH);
        float s = gm[o] * rsqrtf(var + EPS);
        for (int b = 0; b < BATCH; b++) {
            float v = (z[b] - mean) * s + betam[o];
            out[b * 512 + o] = (v > 0.f) ? v : 0.2f * v;
        }
    }
}

extern "C" void kernel_launch(void* const* d_in, const int* in_sizes, int n_in,
                              void* d_out, int out_size, void* d_ws, size_t ws_size,
                              hipStream_t stream) {
    const float* x = (const float*)d_in[0];
    const float* Wm = (const float*)d_in[19];
    const float* bm = (const float*)d_in[20];
    const float* gm = (const float*)d_in[21];
    const float* betam = (const float*)d_in[22];
    float* out = (float*)d_out;

    char* ws = (char*)d_ws;
    // Compact layout — total 67 MB.
    float* G        = (float*)(ws);                                    // [0,16) MB (shared with p)
    float* p        = G;
    float* q        = (float*)(ws + (size_t)(16 << 20));               // [16,32) MB
    float* feat     = (float*)(ws + (size_t)(32 << 20));               // [32,64) MB
    int*   idx      = (int*)  (ws + (size_t)(64 << 20));               // 320 KB
    float* xx       = (float*)(ws + (size_t)(64 << 20) + (384 << 10)); // 16 KB
    float* sc       = (float*)(ws + (size_t)(64 << 20) + (448 << 10)); // 8 KB
    float* pooled   = (float*)(ws + (size_t)(64 << 20) + (512 << 10)); // 64 KB
    float* partials = (float*)(ws + (size_t)(65 << 20));               // [65,67) MB

    const int cins[6]   = {8, 64, 64, 128, 256, 512};
    const int couts[6]  = {64, 64, 128, 256, 512, 1024};
    const int choffs[6] = {0, 64, 128, 256, 512, 1024};

    const float* xin = x;
    size_t bstride = (size_t)8 * NPTS;
    const int NBLK = BATCH * (NPTS / 16);  // 256 n-chunk blocks for stats

    for (int L = 0; L < 6; ++L) {
        int Cin = cins[L], Cout = couts[L], choff = choffs[L];
        const float* W = (const float*)d_in[1 + 3 * L];
        const float* g = (const float*)d_in[2 + 3 * L];
        const float* bb = (const float*)d_in[3 + 3 * L];

        if (Cin >= 256)
            gram128_kernel<<<dim3(NPTS / 128, NPTS / 128, BATCH), 256, 0, stream>>>(xin, Cin, bstride, G, xx);
        else
            gram_kernel<<<dim3(NPTS / 128, NPTS / 64, BATCH), 256, 0, stream>>>(xin, Cin, bstride, G, xx);
        topk_kernel<<<BATCH * NPTS / 4, 256, 0, stream>>>(G, xx, idx);
        if (Cout >= 1024)
            pq128_kernel<<<dim3(Cout / 128, NPTS / 128, BATCH), 256, 0, stream>>>(xin, Cin, bstride, W, Cout, p, q);
        else
            pq_gemm_kernel<<<dim3(Cout / 64, NPTS / 64, BATCH), 256, 0, stream>>>(xin, Cin, bstride, W, Cout, p, q);
        int CA = (Cout < 256) ? Cout : 256;
        int NCH = Cout / CA;
        switch (Cout) {
            case 64:   stats_kernel<64>  <<<dim3(NBLK, 1), 256, 0, stream>>>(p, q, idx, partials); break;
            case 128:  stats_kernel<128> <<<dim3(NBLK, 1), 256, 0, stream>>>(p, q, idx, partials); break;
            case 256:  stats_kernel<256> <<<dim3(NBLK, 1), 256, 0, stream>>>(p, q, idx, partials); break;
            case 512:  stats_kernel<512> <<<dim3(NBLK, 2), 256, 0, stream>>>(p, q, idx, partials); break;
            case 1024: stats_kernel<1024><<<dim3(NBLK, 4), 256, 0, stream>>>(p, q, idx, partials); break;
        }
        scaleshift_kernel<<<(Cout + 255) / 256, 256, 0, stream>>>(partials, g, bb, Cout, NBLK, CA, NCH, sc);
        apply_kernel<<<dim3(Cout / 32, NPTS / 32, BATCH), 256, 0, stream>>>(p, q, idx, sc, Cout, choff, feat);

        xin = feat + (size_t)choff * NPTS;
        bstride = (size_t)FEATC * NPTS;
    }

    pool_kernel<<<BATCH * FEATC, 256, 0, stream>>>(feat, pooled);
    final_kernel<<<512, 256, 0, stream>>>(pooled, Wm, bm, gm, betam, out);
}

// Round 11
// 1083.568 us; speedup vs baseline: 1.2041x; 1.2041x over previous
//
#include <hip/hip_runtime.h>
#include <math.h>

#define BATCH 4
#define NPTS 1024
#define KNN 20
#define EPS 1e-5f
#define FEATC 2048
#define KC 16

// Workspace budget (R4): keep total under 67 MB (99 MB corrupted harness state).
// R8/R9: xx == diag(G) bitwise, folded into gram epilogue.
// R10 post-mortem: 128x128 tiles (128 acc floats/thread) spill regardless of
// __launch_bounds__(256,2) — VGPR_Count pinned at 128, 120+ MB scratch traffic.
// 64x64 (4x4+4x4 acc, 68 VGPR) is the sweet spot; reverted. stats/apply
// gathers vectorized float4 across channels (4x fewer loads, latency-bound).

// ---------------- Gram 64(n) x 128(m), 4x8/thread ----------------
__global__ __launch_bounds__(256, 2)
void gram_kernel(const float* __restrict__ x, int Cin, size_t bstride,
                 float* __restrict__ G, float* __restrict__ xx) {
    // grid: (NPTS/128, NPTS/64, BATCH); block 256 = 16(tn) x 16(tm)
    int b = blockIdx.z;
    int n0 = blockIdx.y * 64;
    int m0 = blockIdx.x * 128;
    const float* xb = x + (size_t)b * bstride;
    __shared__ float As[KC][64];
    __shared__ float Bs[KC][128];
    int tid = threadIdx.x;
    int tn = tid % 16, tm = tid / 16;
    float acc[4][8] = {};

    const int ia = tid * 4, cca = ia >> 6, nna = ia & 63;
    const int ib = tid * 8, ccb = ib >> 7, mmb = ib & 127;
    float4 pa, pb0, pb1;
    auto prefetch = [&](int c0) {
        pa = make_float4(0.f, 0.f, 0.f, 0.f);
        pb0 = make_float4(0.f, 0.f, 0.f, 0.f);
        pb1 = make_float4(0.f, 0.f, 0.f, 0.f);
        if (c0 + cca < Cin) pa = *(const float4*)(xb + (size_t)(c0 + cca) * NPTS + n0 + nna);
        if (c0 + ccb < Cin) {
            const float* r = xb + (size_t)(c0 + ccb) * NPTS + m0 + mmb;
            pb0 = *(const float4*)(r);
            pb1 = *(const float4*)(r + 4);
        }
    };
    prefetch(0);
    for (int c0 = 0; c0 < Cin; c0 += KC) {
        *(float4*)(&As[cca][nna]) = pa;
        *(float4*)(&Bs[ccb][mmb]) = pb0;
        *(float4*)(&Bs[ccb][mmb + 4]) = pb1;
        __syncthreads();
        if (c0 + KC < Cin) prefetch(c0 + KC);
#pragma unroll
        for (int cc = 0; cc < KC; ++cc) {
            float4 a4 = *(const float4*)(&As[cc][tn * 4]);
            float4 b0 = *(const float4*)(&Bs[cc][tm * 8]);
            float4 b1 = *(const float4*)(&Bs[cc][tm * 8 + 4]);
            float a[4] = {a4.x, a4.y, a4.z, a4.w};
            float bb[8] = {b0.x, b0.y, b0.z, b0.w, b1.x, b1.y, b1.z, b1.w};
#pragma unroll
            for (int i = 0; i < 4; i++)
#pragma unroll
                for (int j = 0; j < 8; j++) acc[i][j] += a[i] * bb[j];
        }
        __syncthreads();
    }
    float* Gb = G + (size_t)b * NPTS * NPTS;
#pragma unroll
    for (int i = 0; i < 4; i++) {
        int n = n0 + tn * 4 + i;
        size_t row = (size_t)n * NPTS + m0 + tm * 8;
        *(float4*)(Gb + row)     = make_float4(acc[i][0], acc[i][1], acc[i][2], acc[i][3]);
        *(float4*)(Gb + row + 4) = make_float4(acc[i][4], acc[i][5], acc[i][6], acc[i][7]);
        // diag fold (R8): xx[b][n] = G[b][n][n]
#pragma unroll
        for (int j = 0; j < 8; j++)
            if (n == m0 + tm * 8 + j) xx[b * NPTS + n] = acc[i][j];
    }
}

// ---------------- top-K: one wave per row, barrier-free ----------------
__global__ __launch_bounds__(256)
void topk_kernel(const float* __restrict__ G, const float* __restrict__ xx,
                 int* __restrict__ idx) {
    // grid BATCH*NPTS/4
    int wid = threadIdx.x >> 6, lane = threadIdx.x & 63;
    int t = blockIdx.x * 4 + wid;
    int b = t >> 10, n = t & (NPTS - 1);
    const float* Gr = G + ((size_t)b * NPTS + n) * NPTS;
    const float* xxb = xx + b * NPTS;
    float xxn = xxb[n];
    float d[16];
    int base = lane * 4;
#pragma unroll
    for (int c = 0; c < 4; ++c) {
        float4 gv = *(const float4*)(Gr + c * 256 + base);
        float4 xv = *(const float4*)(xxb + c * 256 + base);
        d[c * 4 + 0] = (2.f * gv.x - xxn) - xv.x;
        d[c * 4 + 1] = (2.f * gv.y - xxn) - xv.y;
        d[c * 4 + 2] = (2.f * gv.z - xxn) - xv.z;
        d[c * 4 + 3] = (2.f * gv.w - xxn) - xv.w;
    }
    int* out = idx + (size_t)t * KNN;
    for (int k = 0; k < KNN; ++k) {
        float bv = d[0]; int bs = 0;
#pragma unroll
        for (int s = 1; s < 16; ++s)
            if (d[s] > bv) { bv = d[s]; bs = s; }
        int bm = ((bs >> 2) << 8) + base + (bs & 3);
#pragma unroll
        for (int off = 32; off >= 1; off >>= 1) {
            float ov = __shfl_xor(bv, off);
            int om = __shfl_xor(bm, off);
            if (ov > bv || (ov == bv && om < bm)) { bv = ov; bm = om; }
        }
        if (lane == 0) out[k] = bm;
        int rel = bm - base;
#pragma unroll
        for (int s = 0; s < 16; ++s)
            if (rel == (((s >> 2) << 8) | (s & 3))) d[s] = -INFINITY;
    }
}

// ---------------- p/q 64x64 tile, 4x4/thread (all layers) ----------------
__global__ __launch_bounds__(256, 2)
void pq_gemm_kernel(const float* __restrict__ x, int Cin, size_t bstride,
                    const float* __restrict__ W, int Cout,
                    float* __restrict__ p, float* __restrict__ q) {
    // grid: (Cout/64, NPTS/64, BATCH); block 256 = 16(tn:o) x 16(tm:n)
    int b = blockIdx.z;
    int o0 = blockIdx.x * 64;
    int n0 = blockIdx.y * 64;
    const float* xb = x + (size_t)b * bstride;
    __shared__ float W1s[KC][64];
    __shared__ float WQs[KC][64];
    __shared__ float Xs[KC][64];
    int tid = threadIdx.x;
    int tn = tid % 16;
    int tm = tid / 16;
    float accp[4][4] = {};
    float accq[4][4] = {};

    const int ix = tid * 4, ccx = ix >> 6, nnx = ix & 63;
    const int r = tid % 64, cg = (tid / 64) * 4;
    const float* Wr = W + (size_t)(o0 + r) * 2 * Cin;
    float4 px, pw1, pw2;
    auto prefetch = [&](int c0) {
        px = make_float4(0.f, 0.f, 0.f, 0.f);
        pw1 = make_float4(0.f, 0.f, 0.f, 0.f);
        pw2 = make_float4(0.f, 0.f, 0.f, 0.f);
        if (c0 + ccx < Cin) px = *(const float4*)(xb + (size_t)(c0 + ccx) * NPTS + n0 + nnx);
        if (c0 + cg < Cin) {
            pw1 = *(const float4*)(Wr + c0 + cg);
            pw2 = *(const float4*)(Wr + Cin + c0 + cg);
        }
    };
    prefetch(0);
    for (int c0 = 0; c0 < Cin; c0 += KC) {
        *(float4*)(&Xs[ccx][nnx]) = px;
        W1s[cg + 0][r] = pw1.x; WQs[cg + 0][r] = pw2.x - pw1.x;
        W1s[cg + 1][r] = pw1.y; WQs[cg + 1][r] = pw2.y - pw1.y;
        W1s[cg + 2][r] = pw1.z; WQs[cg + 2][r] = pw2.z - pw1.z;
        W1s[cg + 3][r] = pw1.w; WQs[cg + 3][r] = pw2.w - pw1.w;
        __syncthreads();
        if (c0 + KC < Cin) prefetch(c0 + KC);
#pragma unroll
        for (int cc = 0; cc < KC; ++cc) {
            float4 wv = *(const float4*)(&W1s[cc][tn * 4]);
            float4 qv = *(const float4*)(&WQs[cc][tn * 4]);
            float4 xv = *(const float4*)(&Xs[cc][tm * 4]);
            float w1[4] = {wv.x, wv.y, wv.z, wv.w};
            float wq[4] = {qv.x, qv.y, qv.z, qv.w};
            float xj[4] = {xv.x, xv.y, xv.z, xv.w};
#pragma unroll
            for (int i = 0; i < 4; i++)
#pragma unroll
                for (int j = 0; j < 4; j++) {
                    accp[i][j] += w1[i] * xj[j];
                    accq[i][j] += wq[i] * xj[j];
                }
        }
        __syncthreads();
    }
#pragma unroll
    for (int j = 0; j < 4; j++) {
        int n = n0 + tm * 4 + j;
        size_t base = ((size_t)b * NPTS + n) * Cout + o0 + tn * 4;
        *(float4*)(p + base) = make_float4(accp[0][j], accp[1][j], accp[2][j], accp[3][j]);
        *(float4*)(q + base) = make_float4(accq[0][j], accq[1][j], accq[2][j], accq[3][j]);
    }
}

// ---------------- stats: BN sum/sumsq, float4 channel gather (R10) ----------------
// CV = Cout/4 channel-threads (each owns 4 consecutive channels), PP subs
// split the 16-point n-chunk; deterministic tree reduce over subs.
template <int COUT>
__global__ void stats_kernel(const float* __restrict__ p, const float* __restrict__ q,
                             const int* __restrict__ idx,
                             float* __restrict__ partials) {
    constexpr int CV = COUT / 4;          // 16..256 channel-float4 threads
    constexpr int PP = 256 / CV;          // 16..1 sub-threads
    constexpr int NCHUNK = 16;
    int bid = blockIdx.x;
    int b = bid / (NPTS / NCHUNK);
    int n0 = (bid % (NPTS / NCHUNK)) * NCHUNK;
    int cl = threadIdx.x % CV;
    int sub = threadIdx.x / CV;
    int c = cl * 4;
    float sx = 0.f, sy = 0.f, sz = 0.f, sw = 0.f;
    float tx = 0.f, ty = 0.f, tz = 0.f, tw = 0.f;
    for (int nl = sub; nl < NCHUNK; nl += PP) {
        size_t nb = (size_t)b * NPTS + n0 + nl;
        const int* ixp = idx + nb * KNN;
        float4 qv = *(const float4*)(q + nb * COUT + c);
        for (int k = 0; k < KNN; ++k) {
            int m = ixp[k];
            float4 pv = *(const float4*)(p + ((size_t)b * NPTS + m) * COUT + c);
            float vx = pv.x + qv.x, vy = pv.y + qv.y, vz = pv.z + qv.z, vw = pv.w + qv.w;
            sx += vx; sy += vy; sz += vz; sw += vw;
            tx += vx * vx; ty += vy * vy; tz += vz * vz; tw += vw * vw;
        }
    }
    if (PP > 1) {
        __shared__ float4 red[256];
        red[threadIdx.x] = make_float4(sx, sy, sz, sw);
        __syncthreads();
        for (int st = PP / 2; st > 0; st >>= 1) {
            if (sub < st) {
                float4 o = red[threadIdx.x + st * CV];
                float4 m = red[threadIdx.x];
                red[threadIdx.x] = make_float4(m.x + o.x, m.y + o.y, m.z + o.z, m.w + o.w);
            }
            __syncthreads();
        }
        if (sub == 0) { float4 m = red[cl]; sx = m.x; sy = m.y; sz = m.z; sw = m.w; }
        __syncthreads();
        red[threadIdx.x] = make_float4(tx, ty, tz, tw);
        __syncthreads();
        for (int st = PP / 2; st > 0; st >>= 1) {
            if (sub < st) {
                float4 o = red[threadIdx.x + st * CV];
                float4 m = red[threadIdx.x];
                red[threadIdx.x] = make_float4(m.x + o.x, m.y + o.y, m.z + o.z, m.w + o.w);
            }
            __syncthreads();
        }
        if (sub == 0) { float4 m = red[cl]; tx = m.x; ty = m.y; tz = m.z; tw = m.w; }
    }
    if (sub == 0) {
        float* outp = partials + (size_t)bid * 2 * COUT;
        *(float4*)(outp + c) = make_float4(sx, sy, sz, sw);
        *(float4*)(outp + COUT + c) = make_float4(tx, ty, tz, tw);
    }
}

// ---------------- BN scale/shift from partials (deterministic serial reduce) ----------------
__global__ void scaleshift_kernel(const float* __restrict__ partials, const float* __restrict__ g,
                                  const float* __restrict__ beta, int Cout, int nblk,
                                  float* __restrict__ sc) {
    int c = blockIdx.x * 256 + threadIdx.x;
    if (c >= Cout) return;
    float s0 = 0.f, s1 = 0.f;
    for (int b = 0; b < nblk; ++b) {
        s0 += partials[(size_t)b * 2 * Cout + c];
        s1 += partials[(size_t)b * 2 * Cout + Cout + c];
    }
    float cnt = (float)(BATCH * NPTS * KNN);
    float mean = s0 / cnt;
    float var = s1 / cnt - mean * mean;
    float s = g[c] * rsqrtf(var + EPS);
    sc[c] = s;
    sc[Cout + c] = beta[c] - mean * s;
}

// ---------------- apply: float4 gather max/min, BN+leaky, transpose (R10) ----------------
__global__ void apply_kernel(const float* __restrict__ p, const float* __restrict__ q,
                             const int* __restrict__ idx, const float* __restrict__ sc,
                             int Cout, int choff, float* __restrict__ feat) {
    // grid: (Cout/32, NPTS/32, BATCH); block 256 = 8 (c-float4) x 32 (n)
    __shared__ float tile[32][33];
    __shared__ int nidx[32][KNN];
    int b = blockIdx.z;
    int c0 = blockIdx.x * 32, n0 = blockIdx.y * 32;
    int tid = threadIdx.x;
    for (int i = tid; i < 32 * KNN; i += 256) {
        int nn = i / KNN, kk = i % KNN;
        nidx[nn][kk] = idx[((size_t)b * NPTS + n0 + nn) * KNN + kk];
    }
    __syncthreads();
    int tx4 = tid % 8, ny = tid / 8;
    int c = c0 + tx4 * 4;
    float4 s4 = *(const float4*)(sc + c);
    float4 sh4 = *(const float4*)(sc + Cout + c);
    size_t nb = (size_t)b * NPTS + n0 + ny;
    float4 qv = *(const float4*)(q + nb * Cout + c);
    float mx[4] = {-INFINITY, -INFINITY, -INFINITY, -INFINITY};
    float mn[4] = {INFINITY, INFINITY, INFINITY, INFINITY};
    for (int k = 0; k < KNN; ++k) {
        int m = nidx[ny][k];
        float4 pv = *(const float4*)(p + ((size_t)b * NPTS + m) * Cout + c);
        float v0 = pv.x + qv.x, v1 = pv.y + qv.y, v2 = pv.z + qv.z, v3 = pv.w + qv.w;
        mx[0] = fmaxf(mx[0], v0); mn[0] = fminf(mn[0], v0);
        mx[1] = fmaxf(mx[1], v1); mn[1] = fminf(mn[1], v1);
        mx[2] = fmaxf(mx[2], v2); mn[2] = fminf(mn[2], v2);
        mx[3] = fmaxf(mx[3], v3); mn[3] = fminf(mn[3], v3);
    }
    float sa[4] = {s4.x, s4.y, s4.z, s4.w};
    float sha[4] = {sh4.x, sh4.y, sh4.z, sh4.w};
#pragma unroll
    for (int u = 0; u < 4; u++) {
        float v = (sa[u] >= 0.f) ? mx[u] : mn[u];
        v = sa[u] * v + sha[u];
        tile[ny][tx4 * 4 + u] = (v > 0.f) ? v : 0.2f * v;
    }
    __syncthreads();
    int wtx = tid % 32, wty = tid / 32;
    for (int i = wty; i < 32; i += 8) {
        feat[((size_t)b * FEATC + choff + c0 + i) * NPTS + n0 + wtx] = tile[wtx][i];
    }
}

// ---------------- pooling: max and mean over N ----------------
__global__ void pool_kernel(const float* __restrict__ feat, float* __restrict__ pooled) {
    // grid BATCH*FEATC, block 256
    int t = blockIdx.x;
    int b = t >> 11, c = t & (FEATC - 1);
    const float* row = feat + (size_t)t * NPTS;
    int tid = threadIdx.x;
    float mx = -INFINITY, sm = 0.f;
    for (int n = tid; n < NPTS; n += 256) { float v = row[n]; mx = fmaxf(mx, v); sm += v; }
    __shared__ float smx[256], ssm[256];
    smx[tid] = mx; ssm[tid] = sm;
    __syncthreads();
    for (int s = 128; s > 0; s >>= 1) {
        if (tid < s) { smx[tid] = fmaxf(smx[tid], smx[tid + s]); ssm[tid] += ssm[tid + s]; }
        __syncthreads();
    }
    if (tid == 0) {
        pooled[b * 4096 + c] = smx[0];
        pooled[b * 4096 + 2048 + c] = ssm[0] * (1.f / NPTS);
    }
}

// ---------------- final GEMV + batch-BN + leaky ----------------
__global__ void final_kernel(const float* __restrict__ pooled, const float* __restrict__ Wm,
                             const float* __restrict__ bm, const float* __restrict__ gm,
                             const float* __restrict__ betam, float* __restrict__ out) {
    // grid 512, block 256
    int o = blockIdx.x;
    int tid = threadIdx.x;
    float acc[BATCH] = {};
    for (int t = tid; t < 4096; t += 256) {
        float w = Wm[(size_t)o * 4096 + t];
#pragma unroll
        for (int b = 0; b < BATCH; b++) acc[b] += w * pooled[b * 4096 + t];
    }
    __shared__ float red[256];
    float zb[BATCH];
    for (int b = 0; b < BATCH; b++) {
        red[tid] = acc[b];
        __syncthreads();
        for (int s = 128; s > 0; s >>= 1) {
            if (tid < s) red[tid] += red[tid + s];
            __syncthreads();
        }
        zb[b] = red[0];
        __syncthreads();
    }
    if (tid == 0) {
        float z[BATCH];
        float mean = 0.f;
        for (int b = 0; b < BATCH; b++) { z[b] = zb[b] + bm[o]; mean += z[b]; }
        mean *= (1.f / BATCH);
        float var = 0.f;
        for (int b = 0; b < BATCH; b++) { float d = z[b] - mean; var += d * d; }
        var *= (1.f / BATCH);
        float s = gm[o] * rsqrtf(var + EPS);
        for (int b = 0; b < BATCH; b++) {
            float v = (z[b] - mean) * s + betam[o];
            out[b * 512 + o] = (v > 0.f) ? v : 0.2f * v;
        }
    }
}

extern "C" void kernel_launch(void* const* d_in, const int* in_sizes, int n_in,
                              void* d_out, int out_size, void* d_ws, size_t ws_size,
                              hipStream_t stream) {
    const float* x = (const float*)d_in[0];
    const float* Wm = (const float*)d_in[19];
    const float* bm = (const float*)d_in[20];
    const float* gm = (const float*)d_in[21];
    const float* betam = (const float*)d_in[22];
    float* out = (float*)d_out;

    char* ws = (char*)d_ws;
    // Compact layout — total 67 MB.
    float* G        = (float*)(ws);                                    // [0,16) MB (shared with p)
    float* p        = G;
    float* q        = (float*)(ws + (size_t)(16 << 20));               // [16,32) MB
    float* feat     = (float*)(ws + (size_t)(32 << 20));               // [32,64) MB
    int*   idx      = (int*)  (ws + (size_t)(64 << 20));               // 320 KB
    float* xx       = (float*)(ws + (size_t)(64 << 20) + (384 << 10)); // 16 KB
    float* sc       = (float*)(ws + (size_t)(64 << 20) + (448 << 10)); // 8 KB
    float* pooled   = (float*)(ws + (size_t)(64 << 20) + (512 << 10)); // 64 KB
    float* partials = (float*)(ws + (size_t)(65 << 20));               // [65,67) MB

    const int cins[6]   = {8, 64, 64, 128, 256, 512};
    const int couts[6]  = {64, 64, 128, 256, 512, 1024};
    const int choffs[6] = {0, 64, 128, 256, 512, 1024};

    const float* xin = x;
    size_t bstride = (size_t)8 * NPTS;
    const int NBLK = BATCH * (NPTS / 16);  // 256 n-chunk blocks for stats

    for (int L = 0; L < 6; ++L) {
        int Cin = cins[L], Cout = couts[L], choff = choffs[L];
        const float* W = (const float*)d_in[1 + 3 * L];
        const float* g = (const float*)d_in[2 + 3 * L];
        const float* bb = (const float*)d_in[3 + 3 * L];

        gram_kernel<<<dim3(NPTS / 128, NPTS / 64, BATCH), 256, 0, stream>>>(xin, Cin, bstride, G, xx);
        topk_kernel<<<BATCH * NPTS / 4, 256, 0, stream>>>(G, xx, idx);
        pq_gemm_kernel<<<dim3(Cout / 64, NPTS / 64, BATCH), 256, 0, stream>>>(xin, Cin, bstride, W, Cout, p, q);
        switch (Cout) {
            case 64:   stats_kernel<64>  <<<NBLK, 256, 0, stream>>>(p, q, idx, partials); break;
            case 128:  stats_kernel<128> <<<NBLK, 256, 0, stream>>>(p, q, idx, partials); break;
            case 256:  stats_kernel<256> <<<NBLK, 256, 0, stream>>>(p, q, idx, partials); break;
            case 512:  stats_kernel<512> <<<NBLK, 256, 0, stream>>>(p, q, idx, partials); break;
            case 1024: stats_kernel<1024><<<NBLK, 256, 0, stream>>>(p, q, idx, partials); break;
        }
        scaleshift_kernel<<<(Cout + 255) / 256, 256, 0, stream>>>(partials, g, bb, Cout, NBLK, sc);
        apply_kernel<<<dim3(Cout / 32, NPTS / 32, BATCH), 256, 0, stream>>>(p, q, idx, sc, Cout, choff, feat);

        xin = feat + (size_t)choff * NPTS;
        bstride = (size_t)FEATC * NPTS;
    }

    pool_kernel<<<BATCH * FEATC, 256, 0, stream>>>(feat, pooled);
    final_kernel<<<512, 256, 0, stream>>>(pooled, Wm, bm, gm, betam, out);
}